// Round 6
// baseline (3862.588 us; speedup 1.0000x reference)
//
#include <hip/hip_runtime.h>
#include <hip/hip_bf16.h>

#define DM_   1024
#define NLAY  8
#define NST   16
#define EE    2048
#define E2    4096
#define RNK   64
#define SEQ   1024
#define NXD   96
#define VOC   256
#define EPS_  1e-5f
#define NCH   64
#define CLEN  16
#define NTHR  256
#define NBAR  96

typedef __attribute__((ext_vector_type(8))) short bf16x8;
typedef __attribute__((ext_vector_type(4))) float f32x4;
typedef __hip_bfloat16 bf16;

__device__ __forceinline__ float sigmoidf_(float x){ return 1.f/(1.f+__expf(-x)); }
__device__ __forceinline__ float softplusf_(float x){ return (x>15.f)?x:log1pf(__expf(x)); }
__device__ __forceinline__ short f2bf_s(float x){
  union { bf16 b; short s; } cv; cv.b = __float2bfloat16(x); return cv.s;
}

__device__ __forceinline__ void gld_lds16(const short* g, short* lds_uniform){
  __builtin_amdgcn_global_load_lds(
      (const __attribute__((address_space(1))) unsigned int*)(const void*)g,
      (__attribute__((address_space(3))) unsigned int*)(void*)lds_uniform,
      16, 0, 0);
}

// ---- fast 2-level grid barrier; per-instance counters (no resets), leaves padded ----
// layout per id: 1024 u32 (4KB): leaf li at [li*16], root at [32*16]
__device__ __forceinline__ void gsync(unsigned* bars, int id, int gdim){
  __syncthreads();
  if (threadIdx.x == 0){
    unsigned* base = bars + (size_t)id*1024;
    int li = blockIdx.x & 31;
    unsigned expect = (unsigned)(gdim >> 5) + (((unsigned)(gdim & 31) > (unsigned)li) ? 1u : 0u);
    unsigned nleaf = (gdim < 32) ? (unsigned)gdim : 32u;
    __threadfence();
    unsigned prev = __hip_atomic_fetch_add(base + li*16, 1u, __ATOMIC_ACQ_REL, __HIP_MEMORY_SCOPE_AGENT);
    if (prev == expect - 1u)
      __hip_atomic_fetch_add(base + 32*16, 1u, __ATOMIC_ACQ_REL, __HIP_MEMORY_SCOPE_AGENT);
    while (__hip_atomic_load(base + 32*16, __ATOMIC_ACQUIRE, __HIP_MEMORY_SCOPE_AGENT) < nleaf)
      __builtin_amdgcn_s_sleep(1);
    __threadfence();
  }
  __syncthreads();
}

__global__ void k_barinit(unsigned* bars){
  bars[(size_t)blockIdx.x*NTHR + threadIdx.x] = 0u;
}

struct Params {
  const int* ids; const float* emb; const float* Wxz; const float* cw; const float* cb;
  const float* Wx; const float* Wdt; const float* dtb; const float* Alog; const float* Dp;
  const float* Wout; const float* nw; const float* fnw; const float* lmw;
  bf16 *wxz_bf, *wout_bf, *wx_bf, *wdt_bf, *lm_bf;
  float *h, *hslab; bf16 *u_bf;
  float *xzb, *xact; bf16 *x_bf;
  float *xdbl, *dtbuf, *S, *dtsum;
  bf16 *y_bf; float *out;
  unsigned* bars;
};

// ---- tiled transpose f32 (R,C) -> bf16 (C,R), grid-stride ----
__device__ void t_job(const float* in, bf16* out, int R, int C, int L, char* smem, int gdim){
  float (*tile)[33] = (float(*)[33])smem;
  int tC = C >> 5, tR = R >> 5;
  int per = tC * tR, total = per * L;
  int tx = threadIdx.x & 31, ty = threadIdx.x >> 5;
  for (int it = blockIdx.x; it < total; it += gdim){
    int l = it / per, rem = it - l*per;
    int tc = rem % tC, tr = rem / tC;
    const float* inp = in + (size_t)l*R*C;
    bf16* outp = out + (size_t)l*R*C;
    int c0 = tc*32, r0 = tr*32;
    __syncthreads();
#pragma unroll
    for (int j = 0; j < 4; j++)
      tile[ty + j*8][tx] = inp[(size_t)(r0+ty+j*8)*C + c0+tx];
    __syncthreads();
#pragma unroll
    for (int j = 0; j < 4; j++)
      outp[(size_t)(c0+ty+j*8)*R + r0+tx] = __float2bfloat16(tile[tx][ty+j*8]);
  }
}

// ---- rmsnorm phase: mode 0 = embed+rms, 1..7 = residual+rms, NLAY = final (+zero out) ----
__device__ void rms_phase(const Params& P, int mode, char* smem, int gdim){
  float* red = (float*)smem;
  const float* w = (mode == NLAY) ? P.fnw : (P.nw + (size_t)mode*DM_);
  int tid = threadIdx.x;
  for (int t = blockIdx.x; t < SEQ; t += gdim){
    float* hp = P.h + (size_t)t*DM_;
    float v[4]; float ss = 0.f;
    __syncthreads();
#pragma unroll
    for (int j = 0; j < 4; j++){
      int i = tid + j*256;
      float x;
      if (mode == 0){ x = P.emb[(size_t)P.ids[t]*DM_ + i]; hp[i] = x; }
      else { x = hp[i] + P.hslab[(size_t)t*DM_ + i] + P.hslab[(size_t)(SEQ+t)*DM_ + i]; hp[i] = x; }
      v[j] = x; ss += x*x;
    }
#pragma unroll
    for (int o = 32; o > 0; o >>= 1) ss += __shfl_down(ss, o, 64);
    if ((tid & 63) == 0) red[tid >> 6] = ss;
    __syncthreads();
    float sc = rsqrtf((red[0]+red[1]+red[2]+red[3])*(1.f/DM_) + EPS_);
    bf16* up = P.u_bf + (size_t)t*DM_;
#pragma unroll
    for (int j = 0; j < 4; j++){
      int i = tid + j*256;
      up[i] = __float2bfloat16(v[j]*sc*w[i]);
    }
  }
  if (mode == NLAY){
    int stride = gdim*NTHR;
    for (int i = blockIdx.x*NTHR + tid; i < SEQ*VOC; i += stride) P.out[i] = 0.f;
  }
}

// ---- GEMM core: A (M,K) bf16, Bt (N,K) bf16, dbuf LDS via global_load_lds ----
template<int BM,int BN,int NWM,int NWN>
__device__ __forceinline__ void gemm_core(
    const short* __restrict__ A, const short* __restrict__ Bt, int K,
    int m0, int n0, int kbeg, int nk, short* As, short* Bs,
    f32x4 (&acc)[(BM/NWM)/16][(BN/NWN)/16])
{
  constexpr int BK = 64;
  constexpr int WM = BM/NWM, WN = BN/NWN;
  constexpr int MT = WM/16, NT = WN/16;
  constexpr int ABY = BM*BK*2, BBY = BN*BK*2;
  constexpr int AISS = ABY/4096, BISS = BBY/4096;
  const int tid = threadIdx.x, lane = tid & 63, wave = tid >> 6;
  const int wr = wave / NWN, wc = wave % NWN;
  const int lrow = lane & 15, lq = lane >> 4;
  const int wbase = (tid & ~63) * 16;

#pragma unroll
  for (int i = 0; i < MT; i++)
#pragma unroll
    for (int j = 0; j < NT; j++) acc[i][j] = (f32x4){0.f,0.f,0.f,0.f};

  auto stage = [&](int k0, int buf){
    short* Ad = As + buf*(BM*BK);
    short* Bd = Bs + buf*(BN*BK);
#pragma unroll
    for (int i = 0; i < AISS; i++){
      int off = i*4096 + tid*16;
      int row = off >> 7;
      int kc  = ((off >> 4) & 7) ^ (row & 7);
      gld_lds16(A + (size_t)(m0+row)*K + k0 + kc*8, Ad + ((i*4096 + wbase) >> 1));
    }
#pragma unroll
    for (int i = 0; i < BISS; i++){
      int off = i*4096 + tid*16;
      int row = off >> 7;
      int kc  = ((off >> 4) & 7) ^ (row & 7);
      gld_lds16(Bt + (size_t)(n0+row)*K + k0 + kc*8, Bd + ((i*4096 + wbase) >> 1));
    }
  };

  stage(kbeg, 0);
  __syncthreads();
  for (int it = 0; it < nk; it++){
    int cur = it & 1;
    if (it + 1 < nk) stage(kbeg + (it+1)*BK, cur ^ 1);
    const short* Ac = As + cur*(BM*BK);
    const short* Bc = Bs + cur*(BN*BK);
#pragma unroll
    for (int s = 0; s < 2; s++){
      bf16x8 af[MT], bfr[NT];
#pragma unroll
      for (int mt = 0; mt < MT; mt++){
        int row = wr*WM + mt*16 + lrow;
        int cc = (s*4 + lq) ^ (row & 7);
        af[mt] = *(const bf16x8*)(Ac + row*BK + cc*8);
      }
#pragma unroll
      for (int nt = 0; nt < NT; nt++){
        int row = wc*WN + nt*16 + lrow;
        int cc = (s*4 + lq) ^ (row & 7);
        bfr[nt] = *(const bf16x8*)(Bc + row*BK + cc*8);
      }
#pragma unroll
      for (int mt = 0; mt < MT; mt++)
#pragma unroll
        for (int nt = 0; nt < NT; nt++)
          acc[mt][nt] = __builtin_amdgcn_mfma_f32_16x16x32_bf16(af[mt], bfr[nt], acc[mt][nt], 0,0,0);
    }
    __syncthreads();
  }
}

// ---- phase: xz = u @ Wxz  (tiles: 16 x 64 = 1024) ----
__device__ void wxz_phase(const Params& P, int l, char* smem, int gdim){
  short* As = (short*)smem;
  short* Bs = (short*)(smem + 16384);
  const short* A  = (const short*)P.u_bf;
  const short* Bt = (const short*)(P.wxz_bf + (size_t)l*E2*DM_);
  int lane = threadIdx.x & 63, wave = threadIdx.x >> 6;
  int wr = wave >> 1, wc = wave & 1, lrow = lane & 15, lq = lane >> 4;
  for (int tile = blockIdx.x; tile < 16*64; tile += gdim){
    int mi = tile >> 6, ni = tile & 63;
    f32x4 acc[2][2];
    gemm_core<64,64,2,2>(A, Bt, DM_, mi*64, ni*64, 0, DM_/64, As, Bs, acc);
#pragma unroll
    for (int mt = 0; mt < 2; mt++){
      int row = mi*64 + wr*32 + mt*16 + lq*4;
#pragma unroll
      for (int nt = 0; nt < 2; nt++){
        int col = ni*64 + wc*32 + nt*16 + lrow;
#pragma unroll
        for (int r = 0; r < 4; r++)
          P.xzb[(size_t)(row+r)*E2 + col] = acc[mt][nt][r];
      }
    }
  }
}

// ---- phase: conv + silu (+ zero xdbl), grid-stride ----
__device__ void conv_phase(const Params& P, int l, int gdim){
  int stride = gdim*NTHR;
  int gtid = blockIdx.x*NTHR + threadIdx.x;
  const float* cwl = P.cw + (size_t)l*EE*4;
  const float* cbl = P.cb + (size_t)l*EE;
  for (int idx = gtid; idx < SEQ*EE; idx += stride){
    int t = idx >> 11, e = idx & 2047;
    float4 w4 = *(const float4*)(cwl + (size_t)e*4);
    float acc = cbl[e];
    const float* col = P.xzb + e;
    if (t >= 3){
      acc += col[(size_t)(t-3)*E2]*w4.x + col[(size_t)(t-2)*E2]*w4.y
           + col[(size_t)(t-1)*E2]*w4.z + col[(size_t)t*E2]*w4.w;
    } else {
      const float* wp = (const float*)&w4;
#pragma unroll
      for (int k = 0; k < 4; k++){ int tt = t-3+k; if (tt >= 0) acc += col[(size_t)tt*E2]*wp[k]; }
    }
    float xv = acc * sigmoidf_(acc);
    P.xact[idx] = xv;
    P.x_bf[idx] = __float2bfloat16(xv);
  }
  for (int i = gtid; i < SEQ*NXD; i += stride) P.xdbl[i] = 0.f;
}

// ---- phase: xdbl += x @ Wx (split-16 K, atomic; tiles 32 x 16 = 512) ----
__device__ void wx_phase(const Params& P, int l, char* smem, int gdim){
  short* As = (short*)smem;           // 2*32*64*2 = 8K
  short* Bs = (short*)(smem + 8192);  // 2*96*64*2 = 24K
  const short* A  = (const short*)P.x_bf;
  const short* Bt = (const short*)(P.wx_bf + (size_t)l*NXD*EE);
  int lane = threadIdx.x & 63, wave = threadIdx.x >> 6;
  int wr = wave >> 1, wc = wave & 1, lrow = lane & 15, lq = lane >> 4;
  for (int tile = blockIdx.x; tile < 512; tile += gdim){
    int z = tile & 15, mi = tile >> 4;
    f32x4 acc[1][3];
    gemm_core<32,96,2,2>(A, Bt, EE, mi*32, 0, z*128, 2, As, Bs, acc);
    int row = mi*32 + wr*16 + lq*4;
#pragma unroll
    for (int nt = 0; nt < 3; nt++){
      int col = wc*48 + nt*16 + lrow;
#pragma unroll
      for (int r = 0; r < 4; r++)
        atomicAdd(&P.xdbl[(size_t)(row+r)*NXD + col], acc[0][nt][r]);
    }
  }
}

// ---- phase: dt = softplus(xdbl[:,:64] @ Wdt + bias); tiles 16 x 32 = 512 ----
__device__ void dt_phase(const Params& P, int l, char* smem, int gdim){
  short* As = (short*)smem;           // 64*64*2 = 8K
  short* Bs = (short*)(smem + 8192);  // 8K
  int tid = threadIdx.x;
  int lane = tid & 63, wave = tid >> 6;
  int wr = wave >> 1, wc = wave & 1, lrow = lane & 15, lq = lane >> 4;
  const short* Bt = (const short*)(P.wdt_bf + (size_t)l*EE*RNK);
  const float* bias = P.dtb + (size_t)l*EE;
  for (int tile = blockIdx.x; tile < 512; tile += gdim){
    int mi = tile >> 5, ni = tile & 31;
    int m0 = mi*64, n0 = ni*64;
    __syncthreads();   // previous tile's LDS reads done
    {
      int row = tid >> 2;
      int kq  = (tid & 3) << 4;
      const float* src = P.xdbl + (size_t)(m0+row)*NXD + kq;
      short tmp[16] __attribute__((aligned(16)));
#pragma unroll
      for (int j = 0; j < 16; j++) tmp[j] = f2bf_s(src[j]);
      int c0 = ((kq>>3) + 0) ^ (row & 7);
      int c1 = ((kq>>3) + 1) ^ (row & 7);
      *(bf16x8*)(As + row*64 + c0*8) = *(const bf16x8*)(tmp);
      *(bf16x8*)(As + row*64 + c1*8) = *(const bf16x8*)(tmp + 8);
    }
    {
      int wbase = (tid & ~63) * 16;
#pragma unroll
      for (int i = 0; i < 2; i++){
        int off = i*4096 + tid*16;
        int row = off >> 7;
        int kc  = ((off >> 4) & 7) ^ (row & 7);
        gld_lds16(Bt + (size_t)(n0+row)*RNK + kc*8, Bs + ((i*4096 + wbase) >> 1));
      }
    }
    __syncthreads();
    f32x4 acc[2][2];
#pragma unroll
    for (int i = 0; i < 2; i++)
#pragma unroll
      for (int j = 0; j < 2; j++) acc[i][j] = (f32x4){0.f,0.f,0.f,0.f};
#pragma unroll
    for (int s = 0; s < 2; s++){
      bf16x8 af[2], bfr[2];
#pragma unroll
      for (int mt = 0; mt < 2; mt++){
        int row = wr*32 + mt*16 + lrow;
        int cc = (s*4 + lq) ^ (row & 7);
        af[mt] = *(const bf16x8*)(As + row*64 + cc*8);
      }
#pragma unroll
      for (int nt = 0; nt < 2; nt++){
        int row = wc*32 + nt*16 + lrow;
        int cc = (s*4 + lq) ^ (row & 7);
        bfr[nt] = *(const bf16x8*)(Bs + row*64 + cc*8);
      }
#pragma unroll
      for (int mt = 0; mt < 2; mt++)
#pragma unroll
        for (int nt = 0; nt < 2; nt++)
          acc[mt][nt] = __builtin_amdgcn_mfma_f32_16x16x32_bf16(af[mt], bfr[nt], acc[mt][nt], 0,0,0);
    }
#pragma unroll
    for (int mt = 0; mt < 2; mt++){
      int row = m0 + wr*32 + mt*16 + lq*4;
#pragma unroll
      for (int nt = 0; nt < 2; nt++){
        int col = n0 + wc*32 + nt*16 + lrow;
#pragma unroll
        for (int r = 0; r < 4; r++)
          P.dtbuf[(size_t)(row+r)*EE + col] = softplusf_(acc[mt][nt][r] + bias[col]);
      }
    }
  }
}

// ---- phase: scan local chunks (units: 8 egroups x 64 chunks = 512) ----
__device__ void scanA_phase(const Params& P, int l, char* smem, int gdim){
  float (*Bsm)[NST] = (float(*)[NST])smem;
  for (int b = blockIdx.x; b < 512; b += gdim){
    int eg = b & 7, c = b >> 3;
    int e = eg*256 + threadIdx.x;
    int t0 = c*CLEN;
    const float* Al = P.Alog + (size_t)l*EE*NST + (size_t)e*NST;
    float Ae[NST];
#pragma unroll
    for (int n = 0; n < NST; n++) Ae[n] = -__expf(Al[n]);
    __syncthreads();
    { int i = threadIdx.x; Bsm[i>>4][i&15] = P.xdbl[(size_t)(t0+(i>>4))*NXD + RNK + (i&15)]; }
    __syncthreads();
    float h[NST];
#pragma unroll
    for (int n = 0; n < NST; n++) h[n] = 0.f;
    float ds = 0.f;
    for (int tt = 0; tt < CLEN; tt++){
      float dtv = P.dtbuf[(size_t)(t0+tt)*EE + e];
      float xv  = P.xact[(size_t)(t0+tt)*EE + e];
      ds += dtv;
      float sx = dtv*xv;
#pragma unroll
      for (int n = 0; n < NST; n++)
        h[n] = __expf(dtv*Ae[n])*h[n] + sx*Bsm[tt][n];
    }
    float* Sp = P.S + ((size_t)c*EE + e)*NST;
#pragma unroll
    for (int n = 0; n < NST; n++) Sp[n] = h[n];
    P.dtsum[(size_t)c*EE + e] = ds;
  }
}

// ---- phase: scan finalize (inline prefix + recompute + gate) ----
__device__ void scanC_phase(const Params& P, int l, char* smem, int gdim){
  float (*Bsm)[NST] = (float(*)[NST])smem;
  float (*Csm)[NST] = (float(*)[NST])(smem + CLEN*NST*4);
  for (int b = blockIdx.x; b < 512; b += gdim){
    int eg = b & 7, c = b >> 3;
    int e = eg*256 + threadIdx.x;
    int t0 = c*CLEN;
    const float* Al = P.Alog + (size_t)l*EE*NST + (size_t)e*NST;
    float Ae[NST];
#pragma unroll
    for (int n = 0; n < NST; n++) Ae[n] = -__expf(Al[n]);
    __syncthreads();
    { int i = threadIdx.x; int tt = i>>4, n = i&15;
      Bsm[tt][n] = P.xdbl[(size_t)(t0+tt)*NXD + RNK + n];
      Csm[tt][n] = P.xdbl[(size_t)(t0+tt)*NXD + RNK + NST + n]; }
    __syncthreads();
    float h[NST];
#pragma unroll
    for (int n = 0; n < NST; n++) h[n] = 0.f;
#pragma unroll 1
    for (int j = 0; j < c; j++){
      float dsj = P.dtsum[(size_t)j*EE + e];
      const float* Sj = P.S + ((size_t)j*EE + e)*NST;
#pragma unroll
      for (int n = 0; n < NST; n++)
        h[n] = __expf(dsj*Ae[n])*h[n] + Sj[n];
    }
    float Dv = P.Dp[(size_t)l*EE + e];
    for (int tt = 0; tt < CLEN; tt++){
      float dtv = P.dtbuf[(size_t)(t0+tt)*EE + e];
      float xv  = P.xact[(size_t)(t0+tt)*EE + e];
      float sx = dtv*xv;
      float y = Dv*xv;
#pragma unroll
      for (int n = 0; n < NST; n++){
        h[n] = __expf(dtv*Ae[n])*h[n] + sx*Bsm[tt][n];
        y += h[n]*Csm[tt][n];
      }
      float zv = P.xzb[(size_t)(t0+tt)*E2 + EE + e];
      y *= zv*sigmoidf_(zv);
      P.y_bf[(size_t)(t0+tt)*EE + e] = __float2bfloat16(y);
    }
  }
}

// ---- phase: hslab[z] = y @ Wout (split-2; tiles 2 x 16 x 16 = 512) ----
__device__ void wout_phase(const Params& P, int l, char* smem, int gdim){
  short* As = (short*)smem;
  short* Bs = (short*)(smem + 16384);
  const short* A  = (const short*)P.y_bf;
  const short* Bt = (const short*)(P.wout_bf + (size_t)l*DM_*EE);
  int lane = threadIdx.x & 63, wave = threadIdx.x >> 6;
  int wr = wave >> 1, wc = wave & 1, lrow = lane & 15, lq = lane >> 4;
  for (int tile = blockIdx.x; tile < 512; tile += gdim){
    int z = tile & 1, mi = (tile >> 1) & 15, ni = (tile >> 5) & 15;
    f32x4 acc[2][2];
    gemm_core<64,64,2,2>(A, Bt, EE, mi*64, ni*64, z*1024, 16, As, Bs, acc);
    float* dst = P.hslab + (size_t)z*SEQ*DM_;
#pragma unroll
    for (int mt = 0; mt < 2; mt++){
      int row = mi*64 + wr*32 + mt*16 + lq*4;
#pragma unroll
      for (int nt = 0; nt < 2; nt++){
        int col = ni*64 + wc*32 + nt*16 + lrow;
#pragma unroll
        for (int r = 0; r < 4; r++)
          dst[(size_t)(row+r)*DM_ + col] = acc[mt][nt][r];
      }
    }
  }
}

// ---- phase: out += u @ lm (split-8, atomic; tiles 8 x 16 x 4 = 512) ----
__device__ void lm_phase(const Params& P, char* smem, int gdim){
  short* As = (short*)smem;
  short* Bs = (short*)(smem + 16384);
  const short* A  = (const short*)P.u_bf;
  const short* Bt = (const short*)P.lm_bf;
  int lane = threadIdx.x & 63, wave = threadIdx.x >> 6;
  int wr = wave >> 1, wc = wave & 1, lrow = lane & 15, lq = lane >> 4;
  for (int tile = blockIdx.x; tile < 512; tile += gdim){
    int z = tile & 7, mi = (tile >> 3) & 15, ni = tile >> 7;
    f32x4 acc[2][2];
    gemm_core<64,64,2,2>(A, Bt, DM_, mi*64, ni*64, z*128, 2, As, Bs, acc);
#pragma unroll
    for (int mt = 0; mt < 2; mt++){
      int row = mi*64 + wr*32 + mt*16 + lq*4;
#pragma unroll
      for (int nt = 0; nt < 2; nt++){
        int col = ni*64 + wc*32 + nt*16 + lrow;
#pragma unroll
        for (int r = 0; r < 4; r++)
          atomicAdd(&P.out[(size_t)(row+r)*VOC + col], acc[mt][nt][r]);
      }
    }
  }
}

// ---- the mega kernel ----
__global__ __launch_bounds__(256,2) void k_mega(Params P){
  __shared__ __align__(16) char smem[32768];
  int gdim = gridDim.x;
  unsigned* bars = P.bars;
  int bid = 0;

  t_job(P.Wxz,  P.wxz_bf,  DM_, E2,  NLAY, smem, gdim);
  t_job(P.Wout, P.wout_bf, EE,  DM_, NLAY, smem, gdim);
  t_job(P.Wx,   P.wx_bf,   EE,  NXD, NLAY, smem, gdim);
  t_job(P.Wdt,  P.wdt_bf,  RNK, EE,  NLAY, smem, gdim);
  t_job(P.lmw,  P.lm_bf,   DM_, VOC, 1,    smem, gdim);
  rms_phase(P, 0, smem, gdim);
  gsync(bars, bid++, gdim);

  for (int l = 0; l < NLAY; l++){
    if (l > 0){ rms_phase(P, l, smem, gdim); gsync(bars, bid++, gdim); }
    wxz_phase(P, l, smem, gdim);   gsync(bars, bid++, gdim);
    conv_phase(P, l, gdim);        gsync(bars, bid++, gdim);
    wx_phase(P, l, smem, gdim);    gsync(bars, bid++, gdim);
    dt_phase(P, l, smem, gdim);    gsync(bars, bid++, gdim);
    scanA_phase(P, l, smem, gdim); gsync(bars, bid++, gdim);
    scanC_phase(P, l, smem, gdim); gsync(bars, bid++, gdim);
    wout_phase(P, l, smem, gdim);  gsync(bars, bid++, gdim);
  }
  rms_phase(P, NLAY, smem, gdim);
  gsync(bars, bid++, gdim);
  lm_phase(P, smem, gdim);
}

// ---------------- launch ----------------
extern "C" void kernel_launch(void* const* d_in, const int* in_sizes, int n_in,
                              void* d_out, int out_size, void* d_ws, size_t ws_size,
                              hipStream_t stream)
{
  Params pa;
  pa.ids  = (const int*)d_in[0];
  pa.emb  = (const float*)d_in[1];
  pa.Wxz  = (const float*)d_in[2];
  pa.cw   = (const float*)d_in[3];
  pa.cb   = (const float*)d_in[4];
  pa.Wx   = (const float*)d_in[5];
  pa.Wdt  = (const float*)d_in[6];
  pa.dtb  = (const float*)d_in[7];
  pa.Alog = (const float*)d_in[8];
  pa.Dp   = (const float*)d_in[9];
  pa.Wout = (const float*)d_in[10];
  pa.nw   = (const float*)d_in[11];
  pa.fnw  = (const float*)d_in[12];
  pa.lmw  = (const float*)d_in[13];

  char* p = (char*)d_ws;
  auto alloc = [&](size_t bytes){ void* r = (void*)p; p += (bytes + 255) & ~(size_t)255; return r; };
  pa.wxz_bf  = (bf16*)alloc((size_t)NLAY*E2*DM_*2);
  pa.wout_bf = (bf16*)alloc((size_t)NLAY*DM_*EE*2);
  pa.wx_bf   = (bf16*)alloc((size_t)NLAY*NXD*EE*2);
  pa.wdt_bf  = (bf16*)alloc((size_t)NLAY*EE*RNK*2);
  pa.lm_bf   = (bf16*)alloc((size_t)VOC*DM_*2);
  pa.h       = (float*)alloc((size_t)SEQ*DM_*4);
  pa.hslab   = (float*)alloc((size_t)2*SEQ*DM_*4);
  pa.u_bf    = (bf16*)alloc((size_t)SEQ*DM_*2);
  pa.xzb     = (float*)alloc((size_t)SEQ*E2*4);
  pa.xact    = (float*)alloc((size_t)SEQ*EE*4);
  pa.x_bf    = (bf16*)alloc((size_t)SEQ*EE*2);
  pa.xdbl    = (float*)alloc((size_t)SEQ*NXD*4);
  pa.dtbuf   = (float*)alloc((size_t)SEQ*EE*4);
  pa.S       = (float*)alloc((size_t)NCH*EE*NST*4);
  pa.dtsum   = (float*)alloc((size_t)NCH*EE*4);
  pa.y_bf    = (bf16*)alloc((size_t)SEQ*EE*2);
  pa.bars    = (unsigned*)alloc((size_t)NBAR*1024*4);
  pa.out     = (float*)d_out;

  // zero barrier state (d_ws is poisoned before every launch)
  k_barinit<<<NBAR*1024/NTHR, NTHR, 0, stream>>>(pa.bars);

  // Runtime-sized cooperative grid (multiple of 32 for the leaf math)
  int dev = 0; hipGetDevice(&dev);
  int cus = 0; hipDeviceGetAttribute(&cus, hipDeviceAttributeMultiprocessorCount, dev);
  int occ = 0; hipOccupancyMaxActiveBlocksPerMultiprocessor(&occ, (const void*)k_mega, NTHR, 0);
  if (occ < 1) occ = 1;
  if (cus < 1) cus = 256;
  long grid = (long)cus * occ;
  if (grid > 512) grid = 512;
  grid &= ~31L;
  if (grid < 32) grid = 32;

  void* args[] = { &pa };
  hipLaunchCooperativeKernel((const void*)k_mega, dim3((int)grid), dim3(NTHR), args, 0, stream);
}

// Round 7
// 1236.907 us; speedup vs baseline: 3.1228x; 3.1228x over previous
//
#include <hip/hip_runtime.h>
#include <hip/hip_bf16.h>

#define DM_   1024
#define NLAY  8
#define NST   16
#define EE    2048
#define E2    4096
#define RNK   64
#define SEQ   1024
#define NXD   96
#define VOC   256
#define EPS_  1e-5f
#define NCH   32
#define CLEN  32
#define NTHR  256

typedef __attribute__((ext_vector_type(8))) short bf16x8;
typedef __attribute__((ext_vector_type(4))) float f32x4;
typedef __hip_bfloat16 bf16;

__device__ __forceinline__ float sigmoidf_(float x){ return 1.f/(1.f+__expf(-x)); }
__device__ __forceinline__ float softplusf_(float x){ return (x>15.f)?x:log1pf(__expf(x)); }
__device__ __forceinline__ short f2bf_s(float x){
  union { bf16 b; short s; } cv; cv.b = __float2bfloat16(x); return cv.s;
}

__device__ __forceinline__ void gld_lds16(const short* g, short* lds_uniform){
  __builtin_amdgcn_global_load_lds(
      (const __attribute__((address_space(1))) unsigned int*)(const void*)g,
      (__attribute__((address_space(3))) unsigned int*)(void*)lds_uniform,
      16, 0, 0);
}

// ---------------- prep: all weight transposes f32 (R,C) -> bf16 (C,R), one dispatch ----------------
__device__ void t_job(const float* in, bf16* out, int R, int C, int L, char* smem, int gdim){
  float (*tile)[33] = (float(*)[33])smem;
  int tC = C >> 5, tR = R >> 5;
  int per = tC * tR, total = per * L;
  int tx = threadIdx.x & 31, ty = threadIdx.x >> 5;
  for (int it = blockIdx.x; it < total; it += gdim){
    int l = it / per, rem = it - l*per;
    int tc = rem % tC, tr = rem / tC;
    const float* inp = in + (size_t)l*R*C;
    bf16* outp = out + (size_t)l*R*C;
    int c0 = tc*32, r0 = tr*32;
    __syncthreads();
#pragma unroll
    for (int j = 0; j < 4; j++)
      tile[ty + j*8][tx] = inp[(size_t)(r0+ty+j*8)*C + c0+tx];
    __syncthreads();
#pragma unroll
    for (int j = 0; j < 4; j++)
      outp[(size_t)(c0+ty+j*8)*R + r0+tx] = __float2bfloat16(tile[tx][ty+j*8]);
  }
}

__global__ __launch_bounds__(256) void k_prep(
    const float* __restrict__ Wxz, const float* __restrict__ Wout,
    const float* __restrict__ Wx, const float* __restrict__ Wdt,
    const float* __restrict__ lmw,
    bf16* wxz_bf, bf16* wout_bf, bf16* wx_bf, bf16* wdt_bf, bf16* lm_bf){
  __shared__ __align__(16) char smem[4352];
  int gdim = gridDim.x;
  t_job(Wxz,  wxz_bf,  DM_, E2,  NLAY, smem, gdim);
  t_job(Wout, wout_bf, EE,  DM_, NLAY, smem, gdim);
  t_job(Wx,   wx_bf,   EE,  NXD, NLAY, smem, gdim);
  t_job(Wdt,  wdt_bf,  RNK, EE,  NLAY, smem, gdim);
  t_job(lmw,  lm_bf,   DM_, VOC, 1,    smem, gdim);
}

// ---------------- fused: h = (embed | h+s0+s1); rmsnorm -> bf16; optional zero d_out ----------------
__global__ void k_rmsnorm_fuse(const int* __restrict__ ids, const float* __restrict__ emb,
                               float* __restrict__ h, const float* __restrict__ s0,
                               const float* __restrict__ s1, const float* __restrict__ w,
                               bf16* __restrict__ u, float* __restrict__ zout){
  int t = blockIdx.x;
  float* hp = h + (size_t)t*DM_;
  float v[4];
  float ss = 0.f;
#pragma unroll
  for (int j = 0; j < 4; j++){
    int i = threadIdx.x + j*256;
    float x;
    if (ids){ x = emb[(size_t)ids[t]*DM_ + i]; hp[i] = x; }
    else { x = hp[i] + s0[(size_t)t*DM_ + i] + s1[(size_t)t*DM_ + i]; hp[i] = x; }
    v[j] = x; ss += x*x;
  }
#pragma unroll
  for (int o = 32; o > 0; o >>= 1) ss += __shfl_down(ss, o, 64);
  __shared__ float red[4];
  if ((threadIdx.x & 63) == 0) red[threadIdx.x >> 6] = ss;
  __syncthreads();
  float tot = red[0]+red[1]+red[2]+red[3];
  float sc = rsqrtf(tot*(1.f/DM_) + EPS_);
  bf16* up = u + (size_t)t*DM_;
#pragma unroll
  for (int j = 0; j < 4; j++){
    int i = threadIdx.x + j*256;
    up[i] = __float2bfloat16(v[j]*sc*w[i]);
  }
  if (zout) zout[(size_t)t*VOC + threadIdx.x] = 0.f;
}

// ---------------- bf16 MFMA GEMM, dbuf LDS via global_load_lds, XOR-swizzled ----------------
// MODE 0: C=acc   4: slab write C[z*M*N+idx]=acc   5: atomicAdd(C,acc)
template<int BM, int BN, int NWM, int NWN, int MODE>
__global__ __launch_bounds__(256) void k_gemm(
    const short* __restrict__ A, const short* __restrict__ Bt, float* __restrict__ C,
    int M, int N, int K, int Ksplit)
{
  constexpr int BK = 64;
  constexpr int WM = BM/NWM, WN = BN/NWN;
  constexpr int MT = WM/16, NT = WN/16;
  constexpr int ABY = BM*BK*2, BBY = BN*BK*2;
  constexpr int AISS = ABY/4096, BISS = BBY/4096;
  __shared__ __align__(16) short As[2][BM*BK];
  __shared__ __align__(16) short Bs[2][BN*BK];
  int tid = threadIdx.x, lane = tid & 63, wave = tid >> 6;
  int wr = wave / NWN, wc = wave % NWN;
  int m0 = blockIdx.x * BM, n0 = blockIdx.y * BN;
  int lrow = lane & 15, lq = lane >> 4;
  int wbase = (tid & ~63) * 16;

  int kbeg = blockIdx.z * Ksplit;
  int nk = Ksplit / BK;

  f32x4 acc[MT][NT];
#pragma unroll
  for (int i = 0; i < MT; i++)
#pragma unroll
    for (int j = 0; j < NT; j++) acc[i][j] = (f32x4){0.f,0.f,0.f,0.f};

  auto stage = [&](int k0, int buf){
#pragma unroll
    for (int i = 0; i < AISS; i++){
      int off = i*4096 + tid*16;
      int row = off >> 7;
      int kc  = ((off >> 4) & 7) ^ (row & 7);
      gld_lds16(A + (size_t)(m0+row)*K + k0 + kc*8, As[buf] + ((i*4096 + wbase) >> 1));
    }
#pragma unroll
    for (int i = 0; i < BISS; i++){
      int off = i*4096 + tid*16;
      int row = off >> 7;
      int kc  = ((off >> 4) & 7) ^ (row & 7);
      gld_lds16(Bt + (size_t)(n0+row)*K + k0 + kc*8, Bs[buf] + ((i*4096 + wbase) >> 1));
    }
  };

  stage(kbeg, 0);
  __syncthreads();
  for (int it = 0; it < nk; it++){
    int cur = it & 1;
    if (it + 1 < nk) stage(kbeg + (it+1)*BK, cur ^ 1);
#pragma unroll
    for (int s = 0; s < 2; s++){
      bf16x8 af[MT], bfr[NT];
#pragma unroll
      for (int mt = 0; mt < MT; mt++){
        int row = wr*WM + mt*16 + lrow;
        int cc = (s*4 + lq) ^ (row & 7);
        af[mt] = *(const bf16x8*)(As[cur] + row*BK + cc*8);
      }
#pragma unroll
      for (int nt = 0; nt < NT; nt++){
        int row = wc*WN + nt*16 + lrow;
        int cc = (s*4 + lq) ^ (row & 7);
        bfr[nt] = *(const bf16x8*)(Bs[cur] + row*BK + cc*8);
      }
#pragma unroll
      for (int mt = 0; mt < MT; mt++)
#pragma unroll
        for (int nt = 0; nt < NT; nt++)
          acc[mt][nt] = __builtin_amdgcn_mfma_f32_16x16x32_bf16(af[mt], bfr[nt], acc[mt][nt], 0,0,0);
    }
    __syncthreads();
  }

  size_t slab = (MODE == 4) ? (size_t)blockIdx.z * M * N : 0;
#pragma unroll
  for (int mt = 0; mt < MT; mt++){
    int row = m0 + wr*WM + mt*16 + lq*4;
#pragma unroll
    for (int nt = 0; nt < NT; nt++){
      int col = n0 + wc*WN + nt*16 + lrow;
#pragma unroll
      for (int r = 0; r < 4; r++){
        float v = acc[mt][nt][r];
        size_t idx = slab + (size_t)(row + r)*N + col;
        if (MODE == 5) atomicAdd(&C[idx], v);
        else C[idx] = v;
      }
    }
  }
}

// ---------------- conv(K=4) + bias + silu; also zeros xdbl for wx atomics ----------------
__global__ void k_conv_silu(const float* __restrict__ xz, const float* __restrict__ cw,
                            const float* __restrict__ cb, float* __restrict__ xact,
                            bf16* __restrict__ xbf, float* __restrict__ xdbl){
  int t = blockIdx.y;
  int e = blockIdx.x*256 + threadIdx.x;
  float4 w4 = *(const float4*)(cw + (size_t)e*4);
  float acc = cb[e];
  if (t >= 3){
    acc += xz[(size_t)(t-3)*E2 + e]*w4.x + xz[(size_t)(t-2)*E2 + e]*w4.y
         + xz[(size_t)(t-1)*E2 + e]*w4.z + xz[(size_t)t*E2 + e]*w4.w;
  } else {
    const float* wp = (const float*)&w4;
#pragma unroll
    for (int k = 0; k < 4; k++){ int tt = t-3+k; if (tt >= 0) acc += xz[(size_t)tt*E2 + e]*wp[k]; }
  }
  float xv = acc * sigmoidf_(acc);
  size_t id = (size_t)t*EE + e;
  xact[id] = xv;
  xbf[id] = __float2bfloat16(xv);
  if (id < SEQ*NXD) xdbl[id] = 0.f;
}

// ---------------- fused dt GEMM (A cast in-staging) + scanA epilogue ----------------
// grid (SEQ/64, EE/64); tile 64t x 64e; 2 scan chunks (CLEN=32) per tile.
__global__ __launch_bounds__(256) void k_dt_scanA(
    const float* __restrict__ xdbl, const short* __restrict__ WdtT,
    const float* __restrict__ dtb, const float* __restrict__ Alog,
    const float* __restrict__ xact, float* __restrict__ dtbuf,
    float* __restrict__ S, float* __restrict__ dtsum)
{
  __shared__ __align__(16) char smem[22528];
  short* As = (short*)smem;            // 8K
  short* Bs = (short*)(smem + 8192);   // 8K
  float (*dts)[65]  = (float(*)[65])smem;            // 64x65 f32 (reuse)
  float (*Bcol)[17] = (float(*)[17])(smem + 16640);  // 64x17 f32
  int tid = threadIdx.x;
  int lane = tid & 63, wave = tid >> 6;
  int wr = wave >> 1, wc = wave & 1, lrow = lane & 15, lq = lane >> 4;
  int m0 = blockIdx.x*64, n0 = blockIdx.y*64;

  {
    int row = tid >> 2;
    int kq  = (tid & 3) << 4;
    const float* src = xdbl + (size_t)(m0+row)*NXD + kq;
    short tmp[16] __attribute__((aligned(16)));
#pragma unroll
    for (int j = 0; j < 16; j++) tmp[j] = f2bf_s(src[j]);
    int c0 = ((kq>>3) + 0) ^ (row & 7);
    int c1 = ((kq>>3) + 1) ^ (row & 7);
    *(bf16x8*)(As + row*64 + c0*8) = *(const bf16x8*)(tmp);
    *(bf16x8*)(As + row*64 + c1*8) = *(const bf16x8*)(tmp + 8);
  }
  {
    int wbase = (tid & ~63) * 16;
#pragma unroll
    for (int i = 0; i < 2; i++){
      int off = i*4096 + tid*16;
      int row = off >> 7;
      int kc  = ((off >> 4) & 7) ^ (row & 7);
      gld_lds16(WdtT + (size_t)(n0+row)*RNK + kc*8, Bs + ((i*4096 + wbase) >> 1));
    }
  }
  __syncthreads();
  f32x4 acc[2][2];
#pragma unroll
  for (int i = 0; i < 2; i++)
#pragma unroll
    for (int j = 0; j < 2; j++) acc[i][j] = (f32x4){0.f,0.f,0.f,0.f};
#pragma unroll
  for (int s = 0; s < 2; s++){
    bf16x8 af[2], bfr[2];
#pragma unroll
    for (int mt = 0; mt < 2; mt++){
      int row = wr*32 + mt*16 + lrow;
      int cc = (s*4 + lq) ^ (row & 7);
      af[mt] = *(const bf16x8*)(As + row*64 + cc*8);
    }
#pragma unroll
    for (int nt = 0; nt < 2; nt++){
      int row = wc*32 + nt*16 + lrow;
      int cc = (s*4 + lq) ^ (row & 7);
      bfr[nt] = *(const bf16x8*)(Bs + row*64 + cc*8);
    }
#pragma unroll
    for (int mt = 0; mt < 2; mt++)
#pragma unroll
      for (int nt = 0; nt < 2; nt++)
        acc[mt][nt] = __builtin_amdgcn_mfma_f32_16x16x32_bf16(af[mt], bfr[nt], acc[mt][nt], 0,0,0);
  }
  __syncthreads();   // done with As/Bs; reuse LDS

#pragma unroll
  for (int mt = 0; mt < 2; mt++){
    int rl = wr*32 + mt*16 + lq*4;
#pragma unroll
    for (int nt = 0; nt < 2; nt++){
      int cl = wc*32 + nt*16 + lrow;
#pragma unroll
      for (int r = 0; r < 4; r++){
        float v = softplusf_(acc[mt][nt][r] + dtb[n0 + cl]);
        dtbuf[(size_t)(m0 + rl + r)*EE + n0 + cl] = v;
        dts[rl + r][cl] = v;
      }
    }
  }
  {
    int row = tid >> 2, n4 = (tid & 3) << 2;
    float4 b4 = *(const float4*)(xdbl + (size_t)(m0+row)*NXD + RNK + n4);
    Bcol[row][n4+0] = b4.x; Bcol[row][n4+1] = b4.y;
    Bcol[row][n4+2] = b4.z; Bcol[row][n4+3] = b4.w;
  }
  __syncthreads();

  if (tid < 128){
    int ch = tid >> 6, el = tid & 63;
    int e = n0 + el;
    int c = (m0 >> 5) + ch;
    int t0 = c*CLEN;
    const float* Al = Alog + (size_t)e*NST;
    float Ae[NST];
#pragma unroll
    for (int n = 0; n < NST; n++) Ae[n] = -__expf(Al[n]);
    float h[NST];
#pragma unroll
    for (int n = 0; n < NST; n++) h[n] = 0.f;
    float ds = 0.f;
    for (int tt = 0; tt < CLEN; tt++){
      float dtv = dts[ch*CLEN + tt][el];
      float xv  = xact[(size_t)(t0+tt)*EE + e];
      ds += dtv;
      float sx = dtv*xv;
#pragma unroll
      for (int n = 0; n < NST; n++)
        h[n] = __expf(dtv*Ae[n])*h[n] + sx*Bcol[ch*CLEN + tt][n];
    }
    float* Sp = S + ((size_t)c*EE + e)*NST;
#pragma unroll
    for (int n = 0; n < NST; n++) Sp[n] = h[n];
    dtsum[(size_t)c*EE + e] = ds;
  }
}

// ---------------- scanC: inline chunk prefix + recompute + gate ----------------
__global__ void k_scanC(const float* __restrict__ dt, const float* __restrict__ x,
                        const float* __restrict__ xdbl, const float* __restrict__ Alog,
                        const float* __restrict__ Dp, const float* __restrict__ S,
                        const float* __restrict__ dtsum, const float* __restrict__ xz,
                        bf16* __restrict__ ybf){
  int e = blockIdx.x*256 + threadIdx.x;
  int c = blockIdx.y;
  int t0 = c*CLEN;
  float Ae[NST];
#pragma unroll
  for (int n = 0; n < NST; n++) Ae[n] = -__expf(Alog[(size_t)e*NST + n]);
  __shared__ float Bsm[CLEN][NST], Csm[CLEN][NST];
  for (int i = threadIdx.x; i < CLEN*NST; i += 256){
    int tt = i>>4, n = i&15;
    Bsm[tt][n] = xdbl[(size_t)(t0+tt)*NXD + RNK + n];
    Csm[tt][n] = xdbl[(size_t)(t0+tt)*NXD + RNK + NST + n];
  }
  __syncthreads();
  float h[NST];
#pragma unroll
  for (int n = 0; n < NST; n++) h[n] = 0.f;
  for (int j = 0; j < c; j++){
    float dsj = dtsum[(size_t)j*EE + e];
    const float* Sj = S + ((size_t)j*EE + e)*NST;
#pragma unroll
    for (int n = 0; n < NST; n++)
      h[n] = __expf(dsj*Ae[n])*h[n] + Sj[n];
  }
  float Dv = Dp[e];
  for (int tt = 0; tt < CLEN; tt++){
    float dtv = dt[(size_t)(t0+tt)*EE + e];
    float xv  = x[(size_t)(t0+tt)*EE + e];
    float sx = dtv*xv;
    float y = Dv*xv;
#pragma unroll
    for (int n = 0; n < NST; n++){
      h[n] = __expf(dtv*Ae[n])*h[n] + sx*Bsm[tt][n];
      y += h[n]*Csm[tt][n];
    }
    float zv = xz[(size_t)(t0+tt)*E2 + EE + e];
    y *= zv*sigmoidf_(zv);
    ybf[(size_t)(t0+tt)*EE + e] = __float2bfloat16(y);
  }
}

// ---------------- launch ----------------
extern "C" void kernel_launch(void* const* d_in, const int* in_sizes, int n_in,
                              void* d_out, int out_size, void* d_ws, size_t ws_size,
                              hipStream_t stream)
{
  const int*   ids  = (const int*)d_in[0];
  const float* emb  = (const float*)d_in[1];
  const float* Wxz  = (const float*)d_in[2];
  const float* cw   = (const float*)d_in[3];
  const float* cb   = (const float*)d_in[4];
  const float* Wx   = (const float*)d_in[5];
  const float* Wdt  = (const float*)d_in[6];
  const float* dtb  = (const float*)d_in[7];
  const float* Alog = (const float*)d_in[8];
  const float* Dp   = (const float*)d_in[9];
  const float* Wout = (const float*)d_in[10];
  const float* nw   = (const float*)d_in[11];
  const float* fnw  = (const float*)d_in[12];
  const float* lmw  = (const float*)d_in[13];

  char* p = (char*)d_ws;
  auto alloc = [&](size_t bytes){ void* r = (void*)p; p += (bytes + 255) & ~(size_t)255; return r; };
  bf16* wxz_bf  = (bf16*)alloc((size_t)NLAY*E2*DM_*2);
  bf16* wout_bf = (bf16*)alloc((size_t)NLAY*DM_*EE*2);
  bf16* wx_bf   = (bf16*)alloc((size_t)NLAY*NXD*EE*2);
  bf16* wdt_bf  = (bf16*)alloc((size_t)NLAY*EE*RNK*2);
  bf16* lm_bf   = (bf16*)alloc((size_t)VOC*DM_*2);
  float* h      = (float*)alloc((size_t)SEQ*DM_*4);
  float* hslab  = (float*)alloc((size_t)2*SEQ*DM_*4);
  bf16* u_bf    = (bf16*)alloc((size_t)SEQ*DM_*2);
  float* xzb    = (float*)alloc((size_t)SEQ*E2*4);
  float* xact   = (float*)alloc((size_t)SEQ*EE*4);
  bf16* x_bf    = (bf16*)alloc((size_t)SEQ*EE*2);
  float* xdbl   = (float*)alloc((size_t)SEQ*NXD*4);
  float* dtbuf  = (float*)alloc((size_t)SEQ*EE*4);
  float* Sbuf   = (float*)alloc((size_t)NCH*EE*NST*4);
  float* dtsum  = (float*)alloc((size_t)NCH*EE*4);
  bf16* y_bf    = (bf16*)alloc((size_t)SEQ*EE*2);

  k_prep<<<512, 256, 0, stream>>>(Wxz, Wout, Wx, Wdt, lmw,
                                  wxz_bf, wout_bf, wx_bf, wdt_bf, lm_bf);

  for (int l = 0; l < NLAY; l++){
    k_rmsnorm_fuse<<<SEQ, 256, 0, stream>>>(
        l == 0 ? ids : nullptr, emb, h,
        hslab, hslab + (size_t)SEQ*DM_,
        nw + (size_t)l*DM_, u_bf, nullptr);
    k_gemm<128,64,2,2,0><<<dim3(SEQ/128, E2/64, 1), 256, 0, stream>>>(
        (const short*)u_bf, (const short*)(wxz_bf + (size_t)l*E2*DM_), xzb,
        SEQ, E2, DM_, DM_);
    k_conv_silu<<<dim3(EE/256, SEQ), 256, 0, stream>>>(
        xzb, cw + (size_t)l*EE*4, cb + (size_t)l*EE, xact, x_bf, xdbl);
    k_gemm<32,96,2,2,5><<<dim3(SEQ/32, 1, 16), 256, 0, stream>>>(
        (const short*)x_bf, (const short*)(wx_bf + (size_t)l*NXD*EE), xdbl,
        SEQ, NXD, EE, EE/16);
    k_dt_scanA<<<dim3(SEQ/64, EE/64), 256, 0, stream>>>(
        xdbl, (const short*)(wdt_bf + (size_t)l*EE*RNK), dtb + (size_t)l*EE,
        Alog + (size_t)l*EE*NST, xact, dtbuf, Sbuf, dtsum);
    k_scanC<<<dim3(EE/256, NCH), 256, 0, stream>>>(
        dtbuf, xact, xdbl, Alog + (size_t)l*EE*NST, Dp + (size_t)l*EE,
        Sbuf, dtsum, xzb, y_bf);
    k_gemm<64,64,2,2,4><<<dim3(SEQ/64, DM_/64, 2), 256, 0, stream>>>(
        (const short*)y_bf, (const short*)(wout_bf + (size_t)l*DM_*EE), hslab,
        SEQ, DM_, EE, EE/2);
  }
  k_rmsnorm_fuse<<<SEQ, 256, 0, stream>>>(
      nullptr, emb, h, hslab, hslab + (size_t)SEQ*DM_, fnw, u_bf, (float*)d_out);
  k_gemm<64,64,2,2,5><<<dim3(SEQ/64, VOC/64, 4), 256, 0, stream>>>(
      (const short*)u_bf, (const short*)lm_bf, (float*)d_out,
      SEQ, VOC, DM_, DM_/4);
}